// Round 4
// baseline (131.464 us; speedup 1.0000x reference)
//
#include <hip/hip_runtime.h>
#include <math.h>

#define Bn 4
#define Cn 64
#define On 64
#define Hn 128
#define Wn 128
#define HWn (Hn * Wn)

typedef __attribute__((ext_vector_type(8))) short s16x8;
typedef __attribute__((ext_vector_type(4))) float f32x4;

__device__ __forceinline__ unsigned short f2bf(float f) {
    unsigned u = __float_as_uint(f);
    u += 0x7fffu + ((u >> 16) & 1u);  // RTNE (finite values)
    return (unsigned short)(u >> 16);
}
__device__ __forceinline__ float bf2f(unsigned short u) {
    return __uint_as_float(((unsigned)u) << 16);
}

// ---------------------------------------------------------------------------
// K1: z=0: x -> xt [B,HW,C] bf16; z=1: feat -> ft; z=2: weights ->
//   wdT2 [2s][9k][64oc][32c] bf16, woT2 [2s][9k][32oc][32c] bf16 (oc>=27 -> 0)
// ---------------------------------------------------------------------------
__global__ __launch_bounds__(256) void transpose_all(const float* __restrict__ x,
                                                     const float* __restrict__ feat,
                                                     const float* __restrict__ wdef,
                                                     const float* __restrict__ woff,
                                                     ushort* __restrict__ xt,
                                                     ushort* __restrict__ ft,
                                                     ushort* __restrict__ wdT2,
                                                     ushort* __restrict__ woT2) {
    int t = threadIdx.x;
    if (blockIdx.z == 2) {
        int id = (blockIdx.y * gridDim.x + blockIdx.x) * 256 + t;
        if (id < 36864) {  // [s][k][oc 64][c 32]
            int c2 = id & 31, oc = (id >> 5) & 63, ks = id >> 11;
            int k = ks % 9, s = ks / 9;
            wdT2[id] = f2bf(wdef[(oc * 64 + s * 32 + c2) * 9 + k]);
        } else if (id < 55296) {  // [s][k][oc 32][c 32]
            int i2 = id - 36864;
            int c2 = i2 & 31, oc = (i2 >> 5) & 31, ks = i2 >> 10;
            int k = ks % 9, s = ks / 9;
            woT2[i2] = (oc < 27) ? f2bf(woff[(oc * 64 + s * 32 + c2) * 9 + k]) : (ushort)0;
        }
        return;
    }
    __shared__ float tile[64][65];
    const float* src = blockIdx.z ? feat : x;
    ushort* dst0 = blockIdx.z ? ft : xt;
    int b = blockIdx.y, hw0 = blockIdx.x * 64;
    int lane = t & 63, grp = t >> 6;
    const float* xb = src + (size_t)b * Cn * HWn;
#pragma unroll
    for (int i = 0; i < 16; ++i) {
        int c = grp * 16 + i;
        tile[lane][c] = xb[(size_t)c * HWn + hw0 + lane];  // coalesced along hw
    }
    __syncthreads();
#pragma unroll
    for (int jj = 0; jj < 2; ++jj) {
        int px = jj * 32 + (t >> 3), ch = t & 7;
        s16x8 p;
#pragma unroll
        for (int j = 0; j < 8; ++j) p[j] = (short)f2bf(tile[px][ch * 8 + j]);
        *(s16x8*)(dst0 + ((size_t)(b * HWn + hw0 + px)) * Cn + ch * 8) = p;  // coalesced
    }
}

// ---------------------------------------------------------------------------
// K2: offset conv. R14: mega-pattern restructure.
//  - Window (rows h-1..h+1, cols wb-1..wb+66, ALL 64 ch) staged ONCE via
//    global_load_lds w=16: linear LDS dest, inverse-swizzled source
//    (cidx=(slot-lin)&7) so reads use rotation slot=(c+lin)&7. 204 lins
//    padded to 208 -> 26624 B LDS -> 6 blocks/CU.
//  - NO weight LDS: woT2 (36 KB) read per-tap direct from global (L2/L1-hot),
//    same as mega's wdT2 path. Removes 2x1152-iter staging + 2 barriers.
//  - One DMA-drain barrier -> 36 MFMA straight -> epilogue. 3 barriers total.
//  Block = 64 px x 32 oc (oc>=27 zero-padded), 4 waves x 16 px, acc[2].
// ---------------------------------------------------------------------------
__global__ __launch_bounds__(256, 4) void off_conv_kernel(const ushort* __restrict__ ft,
                                                          const ushort* __restrict__ woT2,
                                                          const float* __restrict__ b_off,
                                                          float* __restrict__ om) {
    __shared__ __align__(16) char smem[26624];
    ushort* s_win = (ushort*)smem;   // 208 lins * 128 B
    float* s_out = (float*)smem;     // [32][68] f32 overlay (8704 B)

    int t = threadIdx.x;
    int wv = t >> 6, l = t & 63;
    int q = l >> 4, r = l & 15;
    int h = blockIdx.x >> 1, wb = (blockIdx.x & 1) * 64;
    int b = blockIdx.y;
    const ushort* ft_b = ft + (size_t)b * HWn * Cn;

    // ---- async window stage: 204 lins x 8 chunks = 1632 j's ----
#pragma unroll
    for (int i = 0; i < 7; ++i) {
        int jb = i * 256 + wv * 64;  // wave-uniform
        if (jb < 1664) {             // waves 2,3 skip the 7th iteration
            int j = jb + l;
            int lin = j >> 3, slot = j & 7;
            int linc = min(lin, 203);
            int cidx = (slot - lin) & 7;  // inverse of read rotation
            int row = linc / 68, col = linc - row * 68;
            int rs = min(max(h - 1 + row, 0), Hn - 1);
            int cs = min(max(wb - 1 + col, 0), Wn - 1);
            const ushort* gp = ft_b + (size_t)(rs * Wn + cs) * Cn + cidx * 8;
            __builtin_amdgcn_global_load_lds(
                (const __attribute__((address_space(1))) unsigned int*)gp,
                (__attribute__((address_space(3))) unsigned int*)(s_win + (size_t)jb * 8),
                16, 0, 0);
        }
    }
    __syncthreads();  // drains DMA

    f32x4 zero = {0.f, 0.f, 0.f, 0.f};
    s16x8 zz = {0, 0, 0, 0, 0, 0, 0, 0};
    f32x4 acc[2];
    acc[0] = zero; acc[1] = zero;

    int px = wv * 16 + r;
#pragma unroll 3
    for (int k = 0; k < 9; ++k) {
        int dy = k / 3 - 1, dx = k % 3 - 1;
        int y = h + dy;
        bool yv = (y >= 0) && (y < Hn);
        int xx = wb + px + dx;
        bool valid = yv && (xx >= 0) && (xx < Wn);
        int lin = (dy + 1) * 68 + px + dx + 1;
#pragma unroll
        for (int s = 0; s < 2; ++s) {
            int c = s * 4 + q;
            s16x8 av = *(const s16x8*)&s_win[lin * 64 + (((c + lin) & 7) << 3)];
            av = valid ? av : zz;
#pragma unroll
            for (int ot = 0; ot < 2; ++ot) {
                s16x8 bv = *(const s16x8*)(woT2 + (size_t)s * 9216
                                           + (size_t)(k * 32 + ot * 16 + r) * 32 + q * 8);
                acc[ot] = __builtin_amdgcn_mfma_f32_16x16x32_bf16(av, bv, acc[ot], 0, 0, 0);
            }
        }
    }
    __syncthreads();  // window reads done; smem becomes s_out

#pragma unroll
    for (int ot = 0; ot < 2; ++ot) {
        int oc = ot * 16 + r;
        float bo = (oc < 27) ? b_off[oc] : 0.f;
#pragma unroll
        for (int reg = 0; reg < 4; ++reg) {
            int p = wv * 16 + q * 4 + reg;
            float v = acc[ot][reg] + bo;
            if (oc >= 18 && oc < 27) v = 1.f / (1.f + __expf(-v));
            s_out[oc * 68 + p] = v;
        }
    }
    __syncthreads();
    for (int idx = t; idx < 27 * 64; idx += 256) {
        int o = idx >> 6, p = idx & 63;
        om[((size_t)b * 27 + o) * HWn + h * Wn + wb + p] = s_out[o * 68 + p];
    }
}

// ---------------------------------------------------------------------------
// K3: mega. Unchanged from R13 (2-row blocks, no interp duplication,
// global_load_lds staging, direct om loads, 3 barriers, XCD swizzle).
// ---------------------------------------------------------------------------
__global__ __launch_bounds__(256, 3) void mega_kernel(const ushort* __restrict__ xt,
                                                      const ushort* __restrict__ wdT2,
                                                      const float* __restrict__ om,
                                                      const float* __restrict__ b_def,
                                                      float* __restrict__ out) {
    __shared__ __align__(16) char smem[28672];
    ushort* s_win = (ushort*)smem;            // 224 lins * 128 B = 28672 B
    float* s_out = (float*)smem;              // [64][68] f32 = 17408 B overlay

    int t = threadIdx.x;
    int wv = t >> 6, l = t & 63;
    int q = l >> 4, r = l & 15;
    int blk = (blockIdx.x & 7) * 128 + (blockIdx.x >> 3);  // XCD band swizzle
    int b = blk >> 8;
    int gi = blk & 255;
    int h = (gi >> 2) << 1;           // even row; block covers rows h, h+1
    int wbase = (gi & 3) << 5;        // 32-col strip
    int rowoff = wv >> 1, pxh = wv & 1;
    int hrow = h + rowoff;
    int pxi = pxh * 16 + r;           // col within strip [0,32)
    float pxif = (float)pxi;
    float rowofff = (float)rowoff;
    const ushort* xt_b = xt + (size_t)b * HWn * Cn;

    // ---- (a) async window stage: global_load_lds, pre-swizzled source ----
#pragma unroll
    for (int i = 0; i < 7; ++i) {
        int jb = i * 256 + wv * 64;  // wave-uniform chunk base
        int j = jb + l;
        int lin = j >> 3, slot = j & 7;
        int linc = min(lin, 215);
        int cidx = (slot - lin) & 7;  // inverse of read rotation
        int row = linc / 36, col = linc - row * 36;
        int rs = min(max(h - 2 + row, 0), Hn - 1);
        int cs = min(max(wbase - 2 + col, 0), Wn - 1);
        const ushort* gp = xt_b + (size_t)(rs * Wn + cs) * Cn + cidx * 8;
        __builtin_amdgcn_global_load_lds(
            (const __attribute__((address_space(1))) unsigned int*)gp,
            (__attribute__((address_space(3))) unsigned int*)(s_win + (size_t)jb * 8),
            16, 0, 0);
    }

    // ---- (b) om: per-lane direct loads (27 planes for my pixel) ----
    const float* om_b = om + ((size_t)b * 27) * HWn + hrow * Wn + wbase + pxi;
    float omv[27];
#pragma unroll
    for (int o = 0; o < 27; ++o) omv[o] = om_b[(size_t)o * HWn];

    // ---- (c) per-wave vote: all taps inside the 6x36 window ----
    bool okp = true;
#pragma unroll
    for (int k = 0; k < 9; ++k) {
        float uy = (float)(k / 3 - 1) + omv[9 + k];
        float ux = pxif + (float)(k % 3 - 1) + omv[k];
        okp = okp && (uy >= -2.f - rowofff) && (uy < 3.f - rowofff)
                  && (ux >= -2.f) && (ux < 33.f);
    }
    int fast = __all(okp) ? 1 : 0;  // per-wave; staging above is unconditional

    __syncthreads();  // drains the DMA (vmcnt) + om loads overlapped above

    f32x4 zero = {0.f, 0.f, 0.f, 0.f};
    f32x4 acc[4];
    acc[0] = zero; acc[1] = zero; acc[2] = zero; acc[3] = zero;

    if (fast) {
#pragma unroll 3
        for (int k = 0; k < 9; ++k) {
            float uy = (float)(k / 3 - 1) + omv[9 + k];
            float ux = pxif + (float)(k % 3 - 1) + omv[k];
            float mv = omv[18 + k];
            float y0f = floorf(uy), x0f = floorf(ux);
            float fy = uy - y0f, fx = ux - x0f;
            int iy = (int)y0f + 2 + rowoff;  // 0..4
            int ix = (int)x0f + 2;           // 0..34
            int yab = hrow + (int)y0f, xab = wbase + (int)x0f;
            bool vy0 = (yab >= 0) && (yab < Hn);
            bool vy1 = (yab + 1 >= 0) && (yab + 1 < Hn);
            bool vx0 = (xab >= 0) && (xab < Wn);
            bool vx1 = (xab + 1 >= 0) && (xab + 1 < Wn);
            float g0 = (vy0 && vx0) ? (1.f - fy) * (1.f - fx) * mv : 0.f;
            float g1 = (vy0 && vx1) ? (1.f - fy) * fx * mv : 0.f;
            float g2 = (vy1 && vx0) ? fy * (1.f - fx) * mv : 0.f;
            float g3 = (vy1 && vx1) ? fy * fx * mv : 0.f;
            int l0 = iy * 36 + ix, l1 = l0 + 1, l2 = l0 + 36, l3 = l0 + 37;
            // weights for this tap (global, L2-hot): full 64 oc
            s16x8 bw[2][4];
#pragma unroll
            for (int s = 0; s < 2; ++s)
#pragma unroll
                for (int ot = 0; ot < 4; ++ot)
                    bw[s][ot] = *(const s16x8*)(wdT2 + (size_t)s * 18432
                                                + (size_t)(k * 64 + ot * 16 + r) * 32 + q * 8);
            s16x8 af[2];
#pragma unroll
            for (int s = 0; s < 2; ++s) {
                int c = s * 4 + q;  // logical chunk
                s16x8 q0 = *(const s16x8*)&s_win[l0 * 64 + (((c + l0) & 7) << 3)];
                s16x8 q1 = *(const s16x8*)&s_win[l1 * 64 + (((c + l1) & 7) << 3)];
                s16x8 q2 = *(const s16x8*)&s_win[l2 * 64 + (((c + l2) & 7) << 3)];
                s16x8 q3 = *(const s16x8*)&s_win[l3 * 64 + (((c + l3) & 7) << 3)];
                s16x8 p;
#pragma unroll
                for (int j = 0; j < 8; ++j) {
                    float rr = g0 * bf2f((unsigned short)q0[j]) + g1 * bf2f((unsigned short)q1[j])
                             + g2 * bf2f((unsigned short)q2[j]) + g3 * bf2f((unsigned short)q3[j]);
                    p[j] = (short)f2bf(rr);
                }
                af[s] = p;
            }
#pragma unroll
            for (int s = 0; s < 2; ++s)
#pragma unroll
                for (int ot = 0; ot < 4; ++ot)
                    acc[ot] = __builtin_amdgcn_mfma_f32_16x16x32_bf16(af[s], bw[s][ot], acc[ot], 0, 0, 0);
        }
    } else {
        // slow path (rare, any-input correct): global gathers + global weights
#pragma unroll 1
        for (int k = 0; k < 9; ++k) {
            float ys = (float)(hrow + k / 3 - 1) + omv[9 + k];
            float xs = (float)(wbase + pxi + k % 3 - 1) + omv[k];
            float mv = omv[18 + k];
            float y0f = floorf(ys), x0f = floorf(xs);
            float fy = ys - y0f, fx = xs - x0f;
            int y0 = (int)y0f, x0 = (int)x0f;
            float g[4];
            int a[4];
#pragma unroll
            for (int n = 0; n < 4; ++n) {
                int yy = y0 + (n >> 1), xx = x0 + (n & 1);
                bool valid = (yy >= 0) && (yy < Hn) && (xx >= 0) && (xx < Wn);
                float wgt = ((n >> 1) ? fy : 1.f - fy) * ((n & 1) ? fx : 1.f - fx) * mv;
                g[n] = valid ? wgt : 0.f;
                int yc = min(max(yy, 0), Hn - 1), xc = min(max(xx, 0), Wn - 1);
                a[n] = (yc * Wn + xc) * Cn;
            }
#pragma unroll
            for (int s = 0; s < 2; ++s) {
                int c = s * 32 + q * 8;
                s16x8 q0 = *(const s16x8*)(xt_b + a[0] + c);
                s16x8 q1 = *(const s16x8*)(xt_b + a[1] + c);
                s16x8 q2 = *(const s16x8*)(xt_b + a[2] + c);
                s16x8 q3 = *(const s16x8*)(xt_b + a[3] + c);
                s16x8 af;
#pragma unroll
                for (int j = 0; j < 8; ++j) {
                    float rr = g[0] * bf2f((unsigned short)q0[j]) + g[1] * bf2f((unsigned short)q1[j])
                             + g[2] * bf2f((unsigned short)q2[j]) + g[3] * bf2f((unsigned short)q3[j]);
                    af[j] = (short)f2bf(rr);
                }
#pragma unroll
                for (int ot = 0; ot < 4; ++ot) {
                    s16x8 bv = *(const s16x8*)(wdT2 + (size_t)s * 18432
                                               + (size_t)(k * 64 + ot * 16 + r) * 32 + q * 8);
                    acc[ot] = __builtin_amdgcn_mfma_f32_16x16x32_bf16(af, bv, acc[ot], 0, 0, 0);
                }
            }
        }
    }
    __syncthreads();  // all window reads done; smem becomes s_out

    // ---- epilogue: bias + ReLU, stage [oc][px64], coalesced store ----
#pragma unroll
    for (int ot = 0; ot < 4; ++ot) {
        int oc = ot * 16 + r;
        float bv = b_def[oc];
        f32x4 vv;
#pragma unroll
        for (int reg = 0; reg < 4; ++reg) vv[reg] = fmaxf(acc[ot][reg] + bv, 0.f);
        *(f32x4*)&s_out[oc * 68 + rowoff * 32 + pxh * 16 + q * 4] = vv;
    }
    __syncthreads();
    {
        int px = t & 63, og = t >> 6;
        int rg = h + (px >> 5);
        float* ob = out + ((size_t)b * On) * HWn + rg * Wn + wbase + (px & 31);
#pragma unroll
        for (int j = 0; j < 16; ++j) {
            int oc = og * 16 + j;
            ob[(size_t)oc * HWn] = s_out[oc * 68 + px];
        }
    }
}

// ---------------------------------------------------------------------------
extern "C" void kernel_launch(void* const* d_in, const int* in_sizes, int n_in,
                              void* d_out, int out_size, void* d_ws, size_t ws_size,
                              hipStream_t stream) {
    const float* x = (const float*)d_in[0];
    const float* feat = (const float*)d_in[1];
    const float* w_off = (const float*)d_in[2];
    const float* b_off = (const float*)d_in[3];
    const float* w_def = (const float*)d_in[4];
    const float* b_def = (const float*)d_in[5];
    float* out = (float*)d_out;

    char* ws = (char*)d_ws;
    ushort* xt = (ushort*)ws;                           // 8 MB [B,HW,C] bf16
    ushort* ft = (ushort*)(ws + 8388608);               // 8 MB [B,HW,C] bf16
    ushort* wdT2 = (ushort*)(ws + 16777216);            // 73728 B [2][9][64][32]
    ushort* woT2 = (ushort*)(ws + 16850944);            // 36864 B [2][9][32][32]
    float* om = (float*)(ws + 16887808);                // 6.75 MB [B][27][H][W]

    hipLaunchKernelGGL(transpose_all, dim3(HWn / 64, Bn, 3), dim3(256), 0, stream,
                       x, feat, w_def, w_off, xt, ft, wdT2, woT2);
    hipLaunchKernelGGL(off_conv_kernel, dim3(Hn * 2, Bn), dim3(256), 0, stream,
                       ft, woT2, b_off, om);
    hipLaunchKernelGGL(mega_kernel, dim3((Bn * HWn) / 64), dim3(256), 0, stream,
                       xt, wdT2, om, b_def, out);
}

// Round 5
// 122.950 us; speedup vs baseline: 1.0692x; 1.0692x over previous
//
#include <hip/hip_runtime.h>
#include <math.h>

#define Bn 4
#define Cn 64
#define On 64
#define Hn 128
#define Wn 128
#define HWn (Hn * Wn)

typedef __attribute__((ext_vector_type(8))) short s16x8;
typedef __attribute__((ext_vector_type(4))) float f32x4;

__device__ __forceinline__ unsigned short f2bf(float f) {
    unsigned u = __float_as_uint(f);
    u += 0x7fffu + ((u >> 16) & 1u);  // RTNE (finite values)
    return (unsigned short)(u >> 16);
}
__device__ __forceinline__ float bf2f(unsigned short u) {
    return __uint_as_float(((unsigned)u) << 16);
}

// ---------------------------------------------------------------------------
// K1: z=0: x -> xt [B,HW,C] bf16; z=1: feat -> ft; z=2: weights ->
//   wdT2 [2s][9k][64oc][32c] bf16, woT2 [2s][9k][32oc][32c] bf16 (oc>=27 -> 0)
// ---------------------------------------------------------------------------
__global__ __launch_bounds__(256) void transpose_all(const float* __restrict__ x,
                                                     const float* __restrict__ feat,
                                                     const float* __restrict__ wdef,
                                                     const float* __restrict__ woff,
                                                     ushort* __restrict__ xt,
                                                     ushort* __restrict__ ft,
                                                     ushort* __restrict__ wdT2,
                                                     ushort* __restrict__ woT2) {
    int t = threadIdx.x;
    if (blockIdx.z == 2) {
        int id = (blockIdx.y * gridDim.x + blockIdx.x) * 256 + t;
        if (id < 36864) {  // [s][k][oc 64][c 32]
            int c2 = id & 31, oc = (id >> 5) & 63, ks = id >> 11;
            int k = ks % 9, s = ks / 9;
            wdT2[id] = f2bf(wdef[(oc * 64 + s * 32 + c2) * 9 + k]);
        } else if (id < 55296) {  // [s][k][oc 32][c 32]
            int i2 = id - 36864;
            int c2 = i2 & 31, oc = (i2 >> 5) & 31, ks = i2 >> 10;
            int k = ks % 9, s = ks / 9;
            woT2[i2] = (oc < 27) ? f2bf(woff[(oc * 64 + s * 32 + c2) * 9 + k]) : (ushort)0;
        }
        return;
    }
    __shared__ float tile[64][65];
    const float* src = blockIdx.z ? feat : x;
    ushort* dst0 = blockIdx.z ? ft : xt;
    int b = blockIdx.y, hw0 = blockIdx.x * 64;
    int lane = t & 63, grp = t >> 6;
    const float* xb = src + (size_t)b * Cn * HWn;
#pragma unroll
    for (int i = 0; i < 16; ++i) {
        int c = grp * 16 + i;
        tile[lane][c] = xb[(size_t)c * HWn + hw0 + lane];  // coalesced along hw
    }
    __syncthreads();
#pragma unroll
    for (int jj = 0; jj < 2; ++jj) {
        int px = jj * 32 + (t >> 3), ch = t & 7;
        s16x8 p;
#pragma unroll
        for (int j = 0; j < 8; ++j) p[j] = (short)f2bf(tile[px][ch * 8 + j]);
        *(s16x8*)(dst0 + ((size_t)(b * HWn + hw0 + px)) * Cn + ch * 8) = p;  // coalesced
    }
}

// ---------------------------------------------------------------------------
// K2 (fused): R15. off_conv folded INTO mega — om never touches global.
//  Per block (2 rows x 32 cols, 4 waves):
//   - DMA both windows at t=0: ft 4x36 (144 lins, issued FIRST) then
//     xt 6x36 (216 lins pad 224, issued LAST). Counted wait vmcnt(7) +
//     raw s_barrier -> ft ready, xt's 7 DMAs stay in flight UNDER phase 1.
//   - Phase 1: om GEMM (M=64 px, N=32 ocp, K=576) from ft window, weights
//     per-tap from global woT2 (36 KB, L2-hot). bias+sigmoid -> s_om bounce
//     (overlays dead ft region). Lanes then read their own 27 om values
//     from LDS (was: 27 serialized global loads).
//   - Phase 2: vote + bilinear interp from xt window + main GEMM (wdT2
//     global), identical math to R13. Epilogue via s_out overlay.
//  LDS: xt 28672 + ft 18432 = 47104 B -> 3 blocks/CU. 5 barriers.
//  Removes: 1 dispatch, om 6.75 MB write+read, per-wave om load chain.
// ---------------------------------------------------------------------------
__global__ __launch_bounds__(256, 3) void mega_kernel(const ushort* __restrict__ xt,
                                                      const ushort* __restrict__ ft,
                                                      const ushort* __restrict__ wdT2,
                                                      const ushort* __restrict__ woT2,
                                                      const float* __restrict__ b_off,
                                                      const float* __restrict__ b_def,
                                                      float* __restrict__ out) {
    __shared__ __align__(16) char smem[47104];
    ushort* s_win = (ushort*)smem;             // xt window: 224 lins * 128 B
    ushort* s_ft = (ushort*)(smem + 28672);    // ft window: 144 lins * 128 B
    float* s_om = (float*)(smem + 28672);      // [27][64] f32 overlay (6912 B)
    float* s_out = (float*)(smem + 28672);     // [64][68] f32 overlay (17408 B)

    int t = threadIdx.x;
    int wv = t >> 6, l = t & 63;
    int q = l >> 4, r = l & 15;
    int blk = (blockIdx.x & 7) * 128 + (blockIdx.x >> 3);  // XCD band swizzle
    int b = blk >> 8;
    int gi = blk & 255;
    int h = (gi >> 2) << 1;           // even row; block covers rows h, h+1
    int wbase = (gi & 3) << 5;        // 32-col strip
    int rowoff = wv >> 1, pxh = wv & 1;
    int hrow = h + rowoff;
    int pxi = pxh * 16 + r;           // col within strip [0,32)
    float pxif = (float)pxi;
    float rowofff = (float)rowoff;
    const ushort* xt_b = xt + (size_t)b * HWn * Cn;
    const ushort* ft_b = ft + (size_t)b * HWn * Cn;

    // ---- (a) DMA ft window FIRST (rows h-1..h+2, cols wbase-2..wbase+33) --
#pragma unroll
    for (int i = 0; i < 5; ++i) {
        int jb = i * 256 + wv * 64;  // wave-uniform
        if (jb < 1152) {             // 144 lins x 8 chunks
            int j = jb + l;
            int lin = j >> 3, slot = j & 7;
            int cidx = (slot - lin) & 7;  // inverse of read rotation
            int row = lin / 36, col = lin - row * 36;
            int rs = min(max(h - 1 + row, 0), Hn - 1);
            int cs = min(max(wbase - 2 + col, 0), Wn - 1);
            const ushort* gp = ft_b + (size_t)(rs * Wn + cs) * Cn + cidx * 8;
            __builtin_amdgcn_global_load_lds(
                (const __attribute__((address_space(1))) unsigned int*)gp,
                (__attribute__((address_space(3))) unsigned int*)(s_ft + (size_t)jb * 8),
                16, 0, 0);
        }
    }
    // ---- (b) DMA xt window LAST (rows h-2..h+3, cols wbase-2..wbase+33) --
#pragma unroll
    for (int i = 0; i < 7; ++i) {
        int jb = i * 256 + wv * 64;
        int j = jb + l;
        int lin = j >> 3, slot = j & 7;
        int linc = min(lin, 215);
        int cidx = (slot - lin) & 7;
        int row = linc / 36, col = linc - row * 36;
        int rs = min(max(h - 2 + row, 0), Hn - 1);
        int cs = min(max(wbase - 2 + col, 0), Wn - 1);
        const ushort* gp = xt_b + (size_t)(rs * Wn + cs) * Cn + cidx * 8;
        __builtin_amdgcn_global_load_lds(
            (const __attribute__((address_space(1))) unsigned int*)gp,
            (__attribute__((address_space(3))) unsigned int*)(s_win + (size_t)jb * 8),
            16, 0, 0);
    }
    // ft complete (its 5 DMAs are oldest); xt's 7 remain in flight
    asm volatile("s_waitcnt vmcnt(7)" ::: "memory");
    __builtin_amdgcn_s_barrier();  // (1) ft window ready for all waves

    f32x4 zero = {0.f, 0.f, 0.f, 0.f};
    s16x8 zz = {0, 0, 0, 0, 0, 0, 0, 0};

    // ---- phase 1: om GEMM from ft window ----
    f32x4 acc2[2];
    acc2[0] = zero; acc2[1] = zero;
    {
        int pxg = wv * 16 + r;            // GEMM M-index (block-local px)
        int rg = pxg >> 5, cg = pxg & 31;
#pragma unroll 3
        for (int k = 0; k < 9; ++k) {
            int dy = k / 3 - 1, dx = k % 3 - 1;
            int y = h + rg + dy;
            bool yv = (y >= 0) && (y < Hn);
            int xx = wbase + cg + dx;
            bool valid = yv && (xx >= 0) && (xx < Wn);
            int lin = (rg + dy + 1) * 36 + cg + dx + 2;
#pragma unroll
            for (int s = 0; s < 2; ++s) {
                int c = s * 4 + q;
                s16x8 av = *(const s16x8*)&s_ft[lin * 64 + (((c + lin) & 7) << 3)];
                av = valid ? av : zz;
#pragma unroll
                for (int ot = 0; ot < 2; ++ot) {
                    s16x8 bv = *(const s16x8*)(woT2 + (size_t)s * 9216
                                               + (size_t)(k * 32 + ot * 16 + r) * 32 + q * 8);
                    acc2[ot] = __builtin_amdgcn_mfma_f32_16x16x32_bf16(av, bv, acc2[ot], 0, 0, 0);
                }
            }
        }
    }
    __syncthreads();  // (2) ft reads done; region becomes s_om

    // ---- bounce: bias + sigmoid -> s_om[27][64] ----
#pragma unroll
    for (int ot = 0; ot < 2; ++ot) {
        int oc = ot * 16 + r;
        if (oc < 27) {
            float bo = b_off[oc];
#pragma unroll
            for (int reg = 0; reg < 4; ++reg) {
                int p = wv * 16 + q * 4 + reg;
                float v = acc2[ot][reg] + bo;
                if (oc >= 18) v = 1.f / (1.f + __expf(-v));
                s_om[oc * 64 + p] = v;
            }
        }
    }
    __syncthreads();  // (3) s_om visible; also drains xt DMA (vmcnt 0)

    // ---- per-lane om values + vote ----
    float omv[27];
#pragma unroll
    for (int o = 0; o < 27; ++o) omv[o] = s_om[o * 64 + rowoff * 32 + pxi];
    bool okp = true;
#pragma unroll
    for (int k = 0; k < 9; ++k) {
        float uy = (float)(k / 3 - 1) + omv[9 + k];
        float ux = pxif + (float)(k % 3 - 1) + omv[k];
        okp = okp && (uy >= -2.f - rowofff) && (uy < 3.f - rowofff)
                  && (ux >= -2.f) && (ux < 33.f);
    }
    int fast = __all(okp) ? 1 : 0;

    f32x4 acc[4];
    acc[0] = zero; acc[1] = zero; acc[2] = zero; acc[3] = zero;

    if (fast) {
#pragma unroll 3
        for (int k = 0; k < 9; ++k) {
            float uy = (float)(k / 3 - 1) + omv[9 + k];
            float ux = pxif + (float)(k % 3 - 1) + omv[k];
            float mv = omv[18 + k];
            float y0f = floorf(uy), x0f = floorf(ux);
            float fy = uy - y0f, fx = ux - x0f;
            int iy = (int)y0f + 2 + rowoff;  // 0..4
            int ix = (int)x0f + 2;           // 0..34
            int yab = hrow + (int)y0f, xab = wbase + (int)x0f;
            bool vy0 = (yab >= 0) && (yab < Hn);
            bool vy1 = (yab + 1 >= 0) && (yab + 1 < Hn);
            bool vx0 = (xab >= 0) && (xab < Wn);
            bool vx1 = (xab + 1 >= 0) && (xab + 1 < Wn);
            float g0 = (vy0 && vx0) ? (1.f - fy) * (1.f - fx) * mv : 0.f;
            float g1 = (vy0 && vx1) ? (1.f - fy) * fx * mv : 0.f;
            float g2 = (vy1 && vx0) ? fy * (1.f - fx) * mv : 0.f;
            float g3 = (vy1 && vx1) ? fy * fx * mv : 0.f;
            int l0 = iy * 36 + ix, l1 = l0 + 1, l2 = l0 + 36, l3 = l0 + 37;
            // weights for this tap (global, L2-hot): full 64 oc
            s16x8 bw[2][4];
#pragma unroll
            for (int s = 0; s < 2; ++s)
#pragma unroll
                for (int ot = 0; ot < 4; ++ot)
                    bw[s][ot] = *(const s16x8*)(wdT2 + (size_t)s * 18432
                                                + (size_t)(k * 64 + ot * 16 + r) * 32 + q * 8);
            s16x8 af[2];
#pragma unroll
            for (int s = 0; s < 2; ++s) {
                int c = s * 4 + q;  // logical chunk
                s16x8 q0 = *(const s16x8*)&s_win[l0 * 64 + (((c + l0) & 7) << 3)];
                s16x8 q1 = *(const s16x8*)&s_win[l1 * 64 + (((c + l1) & 7) << 3)];
                s16x8 q2 = *(const s16x8*)&s_win[l2 * 64 + (((c + l2) & 7) << 3)];
                s16x8 q3 = *(const s16x8*)&s_win[l3 * 64 + (((c + l3) & 7) << 3)];
                s16x8 p;
#pragma unroll
                for (int j = 0; j < 8; ++j) {
                    float rr = g0 * bf2f((unsigned short)q0[j]) + g1 * bf2f((unsigned short)q1[j])
                             + g2 * bf2f((unsigned short)q2[j]) + g3 * bf2f((unsigned short)q3[j]);
                    p[j] = (short)f2bf(rr);
                }
                af[s] = p;
            }
#pragma unroll
            for (int s = 0; s < 2; ++s)
#pragma unroll
                for (int ot = 0; ot < 4; ++ot)
                    acc[ot] = __builtin_amdgcn_mfma_f32_16x16x32_bf16(af[s], bw[s][ot], acc[ot], 0, 0, 0);
        }
    } else {
        // slow path (rare, any-input correct): global gathers + global weights
#pragma unroll 1
        for (int k = 0; k < 9; ++k) {
            float ys = (float)(hrow + k / 3 - 1) + omv[9 + k];
            float xs = (float)(wbase + pxi + k % 3 - 1) + omv[k];
            float mv = omv[18 + k];
            float y0f = floorf(ys), x0f = floorf(xs);
            float fy = ys - y0f, fx = xs - x0f;
            int y0 = (int)y0f, x0 = (int)x0f;
            float g[4];
            int a[4];
#pragma unroll
            for (int n = 0; n < 4; ++n) {
                int yy = y0 + (n >> 1), xx = x0 + (n & 1);
                bool valid = (yy >= 0) && (yy < Hn) && (xx >= 0) && (xx < Wn);
                float wgt = ((n >> 1) ? fy : 1.f - fy) * ((n & 1) ? fx : 1.f - fx) * mv;
                g[n] = valid ? wgt : 0.f;
                int yc = min(max(yy, 0), Hn - 1), xc = min(max(xx, 0), Wn - 1);
                a[n] = (yc * Wn + xc) * Cn;
            }
#pragma unroll
            for (int s = 0; s < 2; ++s) {
                int c = s * 32 + q * 8;
                s16x8 q0 = *(const s16x8*)(xt_b + a[0] + c);
                s16x8 q1 = *(const s16x8*)(xt_b + a[1] + c);
                s16x8 q2 = *(const s16x8*)(xt_b + a[2] + c);
                s16x8 q3 = *(const s16x8*)(xt_b + a[3] + c);
                s16x8 af;
#pragma unroll
                for (int j = 0; j < 8; ++j) {
                    float rr = g[0] * bf2f((unsigned short)q0[j]) + g[1] * bf2f((unsigned short)q1[j])
                             + g[2] * bf2f((unsigned short)q2[j]) + g[3] * bf2f((unsigned short)q3[j]);
                    af[j] = (short)f2bf(rr);
                }
#pragma unroll
                for (int ot = 0; ot < 4; ++ot) {
                    s16x8 bv = *(const s16x8*)(wdT2 + (size_t)s * 18432
                                               + (size_t)(k * 64 + ot * 16 + r) * 32 + q * 8);
                    acc[ot] = __builtin_amdgcn_mfma_f32_16x16x32_bf16(af, bv, acc[ot], 0, 0, 0);
                }
            }
        }
    }
    __syncthreads();  // (4) all reads done; region becomes s_out

    // ---- epilogue: bias + ReLU, stage [oc][px64], coalesced store ----
#pragma unroll
    for (int ot = 0; ot < 4; ++ot) {
        int oc = ot * 16 + r;
        float bv = b_def[oc];
        f32x4 vv;
#pragma unroll
        for (int reg = 0; reg < 4; ++reg) vv[reg] = fmaxf(acc[ot][reg] + bv, 0.f);
        *(f32x4*)&s_out[oc * 68 + rowoff * 32 + pxh * 16 + q * 4] = vv;
    }
    __syncthreads();  // (5)
    {
        int px = t & 63, og = t >> 6;
        int rg = h + (px >> 5);
        float* ob = out + ((size_t)b * On) * HWn + rg * Wn + wbase + (px & 31);
#pragma unroll
        for (int j = 0; j < 16; ++j) {
            int oc = og * 16 + j;
            ob[(size_t)oc * HWn] = s_out[oc * 68 + px];
        }
    }
}

// ---------------------------------------------------------------------------
extern "C" void kernel_launch(void* const* d_in, const int* in_sizes, int n_in,
                              void* d_out, int out_size, void* d_ws, size_t ws_size,
                              hipStream_t stream) {
    const float* x = (const float*)d_in[0];
    const float* feat = (const float*)d_in[1];
    const float* w_off = (const float*)d_in[2];
    const float* b_off = (const float*)d_in[3];
    const float* w_def = (const float*)d_in[4];
    const float* b_def = (const float*)d_in[5];
    float* out = (float*)d_out;

    char* ws = (char*)d_ws;
    ushort* xt = (ushort*)ws;                           // 8 MB [B,HW,C] bf16
    ushort* ft = (ushort*)(ws + 8388608);               // 8 MB [B,HW,C] bf16
    ushort* wdT2 = (ushort*)(ws + 16777216);            // 73728 B [2][9][64][32]
    ushort* woT2 = (ushort*)(ws + 16850944);            // 36864 B [2][9][32][32]

    hipLaunchKernelGGL(transpose_all, dim3(HWn / 64, Bn, 3), dim3(256), 0, stream,
                       x, feat, w_def, w_off, xt, ft, wdT2, woT2);
    hipLaunchKernelGGL(mega_kernel, dim3((Bn * HWn) / 64), dim3(256), 0, stream,
                       xt, ft, wdT2, woT2, b_off, b_def, out);
}